// Round 8
// baseline (461.320 us; speedup 1.0000x reference)
//
#include <hip/hip_runtime.h>

// Soft-DTW forward, B=128, N=M=512, gamma=1.0, fp32.
// One wave per batch; lane k owns columns 8k..8k+7; anti-diagonal wavefront
// in registers (r1 = diag s-1, r2 = diag s-2). Skeleton identical to the
// PASSED round-4 kernel (277us/dispatch); only the cell math and scaling
// machinery differ.
//
// EXP-DOMAIN DP:  E = e^{-R}:  E[i,j] = e^{-d} * (E_diag + E_up + E_left)
//   nv[c] = w * (up + left + diag),  w = 2^(-d*log2e)   [1 exp2/cell,
//   off the dependency chain — no softmin/log on the chain at all]
//
// ROUND-8 scaling (replaces the failed per-lane-frame schemes of R5-R7):
// ONE WAVE-UNIFORM FRAME. Renorm every 16 steps rescales ALL lanes by the
// same 2^-ex, ex = exponent of the wave-wide max (6-hop shfl_xor butterfly).
// With a single shared frame: the cross-lane handoff is a plain shfl of
// plain floats (R4's proven path), boundary values are frame-invariant 0.0f,
// and lane activation needs no frame reconciliation — the failure mode of
// R5/R6/R7 (per-lane frame mismatch at the activation front) cannot exist.
// gexp accumulates the shared exponent (int-valued float, exact).
//
// Junk control: cells with row i >= 512 would keep evolving on clamped D
// rows and could out-grow the live front, hijacking the shared frame. Rows
// >= NN are POISONED to d = 1e4 at load time (register select AFTER the
// unconditional load -> static vmcnt preserved): w = exp2(-14427) == 0
// exactly, so junk values are identically 0 forever — they cannot win the
// renorm max and feed only zeros. Pre-active cells (i < 0) are 0 because
// all their inputs are 0 (no poisoning needed).
//
// Output (lane 63, final step computes cell (511,511)):
//   R = -(log2(r1[7]) + gexp) * ln2   — the kernel's only log.

#define BB 128
#define NN 512
#define MM 512
#define L2E 1.4426950408889634f
#define LN2 0.6931471805599453f
#define DPOIS 1.0e4f

__device__ __forceinline__ int iclamp(int x, int lo, int hi) {
    return x < lo ? lo : (x > hi ? hi : x);
}

template<int PAR, int U>
__device__ __forceinline__ void dostep(
    const float* __restrict__ Db, int k, int jb,
    float (&r1)[8], float (&r2)[8], float4 (&buf)[2][8][2],
    int& irow, float& sh, float& shprev, float& x0)
{
    // prefetch window s+8 (row irow, clamped) — unconditional, static vmcnt
    {
        const int r = iclamp(irow, 0, NN - 1);
        const float4* lp = (const float4*)(Db + ((r << 9) + jb));
        float4 a  = lp[0];
        float4 b4 = lp[1];
        if (irow >= NN) {   // register select after the load (no branch around it)
            a  = make_float4(DPOIS, DPOIS, DPOIS, DPOIS);
            b4 = make_float4(DPOIS, DPOIS, DPOIS, DPOIS);
        }
        buf[PAR ^ 1][U][0] = a;
        buf[PAR ^ 1][U][1] = b4;
        irow += 1;
    }

    float nv[8];
    // cells c = 7..1 (no dependence on the fresh shuffle)
    #pragma unroll
    for (int cc = 7; cc >= 1; --cc) {
        const int c = cc;
        const float up_ = r1[c];
        const float lf  = r1[c - 1];
        const float dg  = r2[c - 1];
        const int par  = (c <= U) ? PAR : (PAR ^ 1);
        const int slot = (c <= U) ? (U - c) : (8 + U - c);
        const float4 f4 = buf[par][slot][c >> 2];
        const float d = ((c & 3) == 0) ? f4.x :
                        ((c & 3) == 1) ? f4.y :
                        ((c & 3) == 2) ? f4.z : f4.w;
        const float w = __builtin_amdgcn_exp2f(-L2E * d);
        nv[c] = w * ((up_ + lf) + dg);
    }
    // cell c = 0: consumes the cross-lane handoff (same shared frame)
    {
        const float up_ = r1[0];
        const float lf  = (k == 0) ? 0.0f : sh;
        const float dg  = (k == 0) ? x0   : shprev;
        const float d   = buf[PAR][U][0].x;
        const float w = __builtin_amdgcn_exp2f(-L2E * d);
        nv[0] = w * ((up_ + lf) + dg);
    }

    x0 = 0.0f;
    #pragma unroll
    for (int c = 0; c < 8; ++c) { r2[c] = r1[c]; r1[c] = nv[c]; }
    shprev = sh;
    sh = __shfl_up(r1[7], 1, 64);   // consumed next step (c=0 last): full slack
}

// Wave-uniform renorm every 16 steps: rescale by 2^-ex where ex is the
// exponent of the WAVE max — every lane applies the same factor, so all
// values (incl. in-flight sh/shprev) stay in one coherent frame.
__device__ __forceinline__ void renorm(float (&r1)[8], float (&r2)[8],
                                       float& sh, float& shprev, float& gexp)
{
    float mx = __builtin_fmaxf(r1[0], r2[0]);
    #pragma unroll
    for (int c = 1; c < 8; ++c)
        mx = __builtin_fmaxf(mx, __builtin_fmaxf(r1[c], r2[c]));
    #pragma unroll
    for (int d = 1; d < 64; d <<= 1)
        mx = __builtin_fmaxf(mx, __shfl_xor(mx, d, 64));
    const int eb = (__float_as_int(mx) >> 23) & 255;
    const int ex = (eb > 0 && eb < 255) ? (eb - 127) : 0;  // 0/denorm/inf: hold
    const float rs = __int_as_float((127 - ex) << 23);     // exact 2^-ex
    #pragma unroll
    for (int c = 0; c < 8; ++c) { r1[c] *= rs; r2[c] *= rs; }
    sh *= rs; shprev *= rs;
    gexp += (float)ex;                                     // int-exact in fp32
}

#define STEP8A(DB) \
    dostep<0,0>(DB,k,jb,r1,r2,buf,irow,sh,shprev,x0); \
    dostep<0,1>(DB,k,jb,r1,r2,buf,irow,sh,shprev,x0); \
    dostep<0,2>(DB,k,jb,r1,r2,buf,irow,sh,shprev,x0); \
    dostep<0,3>(DB,k,jb,r1,r2,buf,irow,sh,shprev,x0); \
    dostep<0,4>(DB,k,jb,r1,r2,buf,irow,sh,shprev,x0); \
    dostep<0,5>(DB,k,jb,r1,r2,buf,irow,sh,shprev,x0); \
    dostep<0,6>(DB,k,jb,r1,r2,buf,irow,sh,shprev,x0); \
    dostep<0,7>(DB,k,jb,r1,r2,buf,irow,sh,shprev,x0);

#define STEP8B(DB) \
    dostep<1,0>(DB,k,jb,r1,r2,buf,irow,sh,shprev,x0); \
    dostep<1,1>(DB,k,jb,r1,r2,buf,irow,sh,shprev,x0); \
    dostep<1,2>(DB,k,jb,r1,r2,buf,irow,sh,shprev,x0); \
    dostep<1,3>(DB,k,jb,r1,r2,buf,irow,sh,shprev,x0); \
    dostep<1,4>(DB,k,jb,r1,r2,buf,irow,sh,shprev,x0); \
    dostep<1,5>(DB,k,jb,r1,r2,buf,irow,sh,shprev,x0); \
    dostep<1,6>(DB,k,jb,r1,r2,buf,irow,sh,shprev,x0); \
    dostep<1,7>(DB,k,jb,r1,r2,buf,irow,sh,shprev,x0);

__launch_bounds__(64, 1)
__global__ void softdtw_wave(const float* __restrict__ D, float* __restrict__ out) {
    const int b = blockIdx.x;
    const int k = threadIdx.x & 63;
    const int jb = k << 3;
    const float* __restrict__ Db = D + (size_t)b * (NN * MM);

    float r1[8], r2[8];
    float4 buf[2][8][2];
    #pragma unroll
    for (int c = 0; c < 8; ++c) { r1[c] = 0.0f; r2[c] = 0.0f; }
    // buf[1][*] is read (for fake cells only) before first write — keep finite.
    #pragma unroll
    for (int p = 0; p < 2; ++p)
        #pragma unroll
        for (int w = 0; w < 8; ++w) {
            buf[p][w][0] = make_float4(0.f, 0.f, 0.f, 0.f);
            buf[p][w][1] = make_float4(0.f, 0.f, 0.f, 0.f);
        }

    // prologue: windows 0..7 (rows w-jb <= 7 < NN: never junk; clamp handles <0)
    #pragma unroll
    for (int w = 0; w < 8; ++w) {
        const int i0 = w - jb;
        const int r = iclamp(i0, 0, NN - 1);
        const float4* lp = (const float4*)(Db + ((r << 9) + jb));
        buf[0][w][0] = lp[0];
        buf[0][w][1] = lp[1];
    }

    int irow = 8 - jb;        // row of window s+8 at s=0
    float sh = 0.0f, shprev = 0.0f;
    float x0 = 1.0f;          // E(R[0,0]=0) = 1 seed; 0 after step 0
    float gexp = 0.0f;        // shared frame exponent (wave-uniform)

    // 63 x 16 = 1008 steps, wave-uniform renorm at each 16-step boundary
    #pragma unroll 1
    for (int qq = 0; qq < 63; ++qq) {
        renorm(r1, r2, sh, shprev, gexp);
        STEP8A(Db)
        STEP8B(Db)
    }
    // tail: steps 1008..1022 (15 steps)
    renorm(r1, r2, sh, shprev, gexp);
    STEP8A(Db)
    dostep<1,0>(Db,k,jb,r1,r2,buf,irow,sh,shprev,x0);
    dostep<1,1>(Db,k,jb,r1,r2,buf,irow,sh,shprev,x0);
    dostep<1,2>(Db,k,jb,r1,r2,buf,irow,sh,shprev,x0);
    dostep<1,3>(Db,k,jb,r1,r2,buf,irow,sh,shprev,x0);
    dostep<1,4>(Db,k,jb,r1,r2,buf,irow,sh,shprev,x0);
    dostep<1,5>(Db,k,jb,r1,r2,buf,irow,sh,shprev,x0);
    dostep<1,6>(Db,k,jb,r1,r2,buf,irow,sh,shprev,x0);

    // E_true = r1[7] * 2^gexp at lane 63;  R = -(log2(r1[7]) + gexp) * ln2
    if (k == 63) {
        out[b] = -(__builtin_amdgcn_logf(r1[7]) + gexp) * LN2;
    }
}

extern "C" void kernel_launch(void* const* d_in, const int* in_sizes, int n_in,
                              void* d_out, int out_size, void* d_ws, size_t ws_size,
                              hipStream_t stream) {
    const float* D = (const float*)d_in[0];
    float* out = (float*)d_out;
    softdtw_wave<<<BB, 64, 0, stream>>>(D, out);
}

// Round 9
// 326.590 us; speedup vs baseline: 1.4125x; 1.4125x over previous
//
#include <hip/hip_runtime.h>

// Soft-DTW forward, B=128, N=M=512, gamma=1.0, fp32.
// One wave per batch; lane k owns columns 8k..8k+7; anti-diagonal wavefront
// in registers (r1 = diag s-1, r2 = diag s-2).
//
// EXP-DOMAIN DP:  E = e^{-R}:  nv[c] = w * (up + left + diag),
//   w = 2^(-d*log2e)  [1 exp2/cell, off the dependency chain].
// Wave-uniform block-FP frame (R8, proven): renorm every 16 steps rescales
// ALL lanes by the same 2^-ex (ex = exponent of wave-wide max via shfl_xor
// butterfly); handoff = plain shfl (shared frame), boundaries = 0.0f.
//
// ROUND-9 fix (post-mortem of R8's 330us, VALUBusy 3.7%): R8 poisoned junk
// rows by cndmask-ing the LOADED VALUES in the same step as the load ->
// forced s_waitcnt vmcnt(0) every step, re-exposing ~500cyc gather latency
// (the R3 failure mode through the back door). Now the load path is
// UNTOUCHED (R4-style: load -> buf regs, first read 8 steps later ->
// compiler pipelines with vmcnt(14)); junk is zeroed AT CONSUMPTION from
// pure index math:  junk  <=>  i = s-jb-c >= 512  <=>
//   sbase + (PAR*8+U-c)  >=  jb+512
// LHS is wave-uniform scalar (free s_add), RHS per-lane constant ->
// 1 v_cmp + 1 v_cndmask per cell on w (off the recurrence chain).
// Junk cells: w=0 -> nv=0 forever; zeros can't win the renorm max; the
// result cell (511,511) has i=511 and is never poisoned. Pre-active cells
// (i<0) are 0 because all inputs are 0.
//
// Output (lane 63, final step): R = -(log2(r1[7]) + gexp) * ln2.

#define BB 128
#define NN 512
#define MM 512
#define L2E 1.4426950408889634f
#define LN2 0.6931471805599453f

__device__ __forceinline__ int iclamp(int x, int lo, int hi) {
    return x < lo ? lo : (x > hi ? hi : x);
}

template<int PAR, int U>
__device__ __forceinline__ void dostep(
    const float* __restrict__ Db, int k, int jb, int sbase, int tq,
    float (&r1)[8], float (&r2)[8], float4 (&buf)[2][8][2],
    int& irow, float& sh, float& shprev, float& x0)
{
    // prefetch window s+8 (row irow, clamped) — unconditional, untouched,
    // static vmcnt; first consumed 8 steps later (vmcnt(14) pipelining).
    {
        const int r = iclamp(irow, 0, NN - 1);
        const float4* lp = (const float4*)(Db + ((r << 9) + jb));
        buf[PAR ^ 1][U][0] = lp[0];
        buf[PAR ^ 1][U][1] = lp[1];
        irow += 1;
    }

    float nv[8];
    // cells c = 7..1 (no dependence on the fresh shuffle)
    #pragma unroll
    for (int cc = 7; cc >= 1; --cc) {
        const int c = cc;
        const float up_ = r1[c];
        const float lf  = r1[c - 1];
        const float dg  = r2[c - 1];
        const int par  = (c <= U) ? PAR : (PAR ^ 1);
        const int slot = (c <= U) ? (U - c) : (8 + U - c);
        const float4 f4 = buf[par][slot][c >> 2];
        const float d = ((c & 3) == 0) ? f4.x :
                        ((c & 3) == 1) ? f4.y :
                        ((c & 3) == 2) ? f4.z : f4.w;
        float w = __builtin_amdgcn_exp2f(-L2E * d);
        const bool junk = (sbase + (PAR * 8 + U - c)) >= tq;  // i >= NN
        w = junk ? 0.0f : w;
        nv[c] = w * ((up_ + lf) + dg);
    }
    // cell c = 0: consumes the cross-lane handoff (same shared frame)
    {
        const float up_ = r1[0];
        const float lf  = (k == 0) ? 0.0f : sh;
        const float dg  = (k == 0) ? x0   : shprev;
        const float d   = buf[PAR][U][0].x;
        float w = __builtin_amdgcn_exp2f(-L2E * d);
        const bool junk = (sbase + (PAR * 8 + U)) >= tq;
        w = junk ? 0.0f : w;
        nv[0] = w * ((up_ + lf) + dg);
    }

    x0 = 0.0f;
    #pragma unroll
    for (int c = 0; c < 8; ++c) { r2[c] = r1[c]; r1[c] = nv[c]; }
    shprev = sh;
    sh = __shfl_up(r1[7], 1, 64);   // consumed next step (c=0 last): full slack
}

// Wave-uniform renorm every 16 steps: rescale by 2^-ex, ex = exponent of
// the wave max of r1 (any wave-uniform pow2 anchor works for range control).
__device__ __forceinline__ void renorm(float (&r1)[8], float (&r2)[8],
                                       float& sh, float& shprev, float& gexp)
{
    float mx = r1[0];
    #pragma unroll
    for (int c = 1; c < 8; ++c) mx = __builtin_fmaxf(mx, r1[c]);
    #pragma unroll
    for (int d = 1; d < 64; d <<= 1)
        mx = __builtin_fmaxf(mx, __shfl_xor(mx, d, 64));
    const int eb = (__float_as_int(mx) >> 23) & 255;
    const int ex = (eb > 0 && eb < 255) ? (eb - 127) : 0;  // 0/denorm/inf: hold
    const float rs = __int_as_float((127 - ex) << 23);     // exact 2^-ex
    #pragma unroll
    for (int c = 0; c < 8; ++c) { r1[c] *= rs; r2[c] *= rs; }
    sh *= rs; shprev *= rs;
    gexp += (float)ex;                                     // int-exact in fp32
}

#define STEP8A(DB) \
    dostep<0,0>(DB,k,jb,sbase,tq,r1,r2,buf,irow,sh,shprev,x0); \
    dostep<0,1>(DB,k,jb,sbase,tq,r1,r2,buf,irow,sh,shprev,x0); \
    dostep<0,2>(DB,k,jb,sbase,tq,r1,r2,buf,irow,sh,shprev,x0); \
    dostep<0,3>(DB,k,jb,sbase,tq,r1,r2,buf,irow,sh,shprev,x0); \
    dostep<0,4>(DB,k,jb,sbase,tq,r1,r2,buf,irow,sh,shprev,x0); \
    dostep<0,5>(DB,k,jb,sbase,tq,r1,r2,buf,irow,sh,shprev,x0); \
    dostep<0,6>(DB,k,jb,sbase,tq,r1,r2,buf,irow,sh,shprev,x0); \
    dostep<0,7>(DB,k,jb,sbase,tq,r1,r2,buf,irow,sh,shprev,x0);

#define STEP8B(DB) \
    dostep<1,0>(DB,k,jb,sbase,tq,r1,r2,buf,irow,sh,shprev,x0); \
    dostep<1,1>(DB,k,jb,sbase,tq,r1,r2,buf,irow,sh,shprev,x0); \
    dostep<1,2>(DB,k,jb,sbase,tq,r1,r2,buf,irow,sh,shprev,x0); \
    dostep<1,3>(DB,k,jb,sbase,tq,r1,r2,buf,irow,sh,shprev,x0); \
    dostep<1,4>(DB,k,jb,sbase,tq,r1,r2,buf,irow,sh,shprev,x0); \
    dostep<1,5>(DB,k,jb,sbase,tq,r1,r2,buf,irow,sh,shprev,x0); \
    dostep<1,6>(DB,k,jb,sbase,tq,r1,r2,buf,irow,sh,shprev,x0); \
    dostep<1,7>(DB,k,jb,sbase,tq,r1,r2,buf,irow,sh,shprev,x0);

__launch_bounds__(64, 1)
__global__ void softdtw_wave(const float* __restrict__ D, float* __restrict__ out) {
    const int b = blockIdx.x;
    const int k = threadIdx.x & 63;
    const int jb = k << 3;
    const int tq = jb + NN;          // junk threshold: s-c >= tq  <=>  i >= NN
    const float* __restrict__ Db = D + (size_t)b * (NN * MM);

    float r1[8], r2[8];
    float4 buf[2][8][2];
    #pragma unroll
    for (int c = 0; c < 8; ++c) { r1[c] = 0.0f; r2[c] = 0.0f; }
    // buf[1][*] is read (fake cells only) before first write — keep finite.
    #pragma unroll
    for (int p = 0; p < 2; ++p)
        #pragma unroll
        for (int w = 0; w < 8; ++w) {
            buf[p][w][0] = make_float4(0.f, 0.f, 0.f, 0.f);
            buf[p][w][1] = make_float4(0.f, 0.f, 0.f, 0.f);
        }

    // prologue: windows 0..7 (rows w-jb <= 7 < NN; clamp handles <0)
    #pragma unroll
    for (int w = 0; w < 8; ++w) {
        const int i0 = w - jb;
        const int r = iclamp(i0, 0, NN - 1);
        const float4* lp = (const float4*)(Db + ((r << 9) + jb));
        buf[0][w][0] = lp[0];
        buf[0][w][1] = lp[1];
    }

    int irow = 8 - jb;        // row of window s+8 at s=0
    float sh = 0.0f, shprev = 0.0f;
    float x0 = 1.0f;          // E(R[0,0]=0) = 1 seed; 0 after step 0
    float gexp = 0.0f;        // shared frame exponent (wave-uniform)

    // 63 x 16 = 1008 steps, wave-uniform renorm at each 16-step boundary
    #pragma unroll 1
    for (int qq = 0; qq < 63; ++qq) {
        const int sbase = qq << 4;      // wave-uniform scalar
        renorm(r1, r2, sh, shprev, gexp);
        STEP8A(Db)
        STEP8B(Db)
    }
    // tail: steps 1008..1022 (15 steps)
    {
        const int sbase = 1008;
        renorm(r1, r2, sh, shprev, gexp);
        STEP8A(Db)
        dostep<1,0>(Db,k,jb,sbase,tq,r1,r2,buf,irow,sh,shprev,x0);
        dostep<1,1>(Db,k,jb,sbase,tq,r1,r2,buf,irow,sh,shprev,x0);
        dostep<1,2>(Db,k,jb,sbase,tq,r1,r2,buf,irow,sh,shprev,x0);
        dostep<1,3>(Db,k,jb,sbase,tq,r1,r2,buf,irow,sh,shprev,x0);
        dostep<1,4>(Db,k,jb,sbase,tq,r1,r2,buf,irow,sh,shprev,x0);
        dostep<1,5>(Db,k,jb,sbase,tq,r1,r2,buf,irow,sh,shprev,x0);
        dostep<1,6>(Db,k,jb,sbase,tq,r1,r2,buf,irow,sh,shprev,x0);
    }

    // E_true = r1[7] * 2^gexp at lane 63;  R = -(log2(r1[7]) + gexp) * ln2
    if (k == 63) {
        out[b] = -(__builtin_amdgcn_logf(r1[7]) + gexp) * LN2;
    }
}

extern "C" void kernel_launch(void* const* d_in, const int* in_sizes, int n_in,
                              void* d_out, int out_size, void* d_ws, size_t ws_size,
                              hipStream_t stream) {
    const float* D = (const float*)d_in[0];
    float* out = (float*)d_out;
    softdtw_wave<<<BB, 64, 0, stream>>>(D, out);
}